// Round 8
// baseline (305.069 us; speedup 1.0000x reference)
//
#include <hip/hip_runtime.h>
#include <hip/hip_bf16.h>
#include <math.h>

// Problem constants: B=4, T=4096, C=1024, H=16, D=64, BLOCK=128
//   M = B*T = 16384 rows
//   GEMM1: [16384,1024] @ [1024,3072] -> qkv
//   attn : 2048 blocks of (128x64) q,k,v, causal-within-block softmax
//   GEMM2: [16384,1024] @ [1024,1024] + bias -> out (fp32)

typedef __bf16 bf16_t;
typedef __bf16 bf16x8 __attribute__((ext_vector_type(8)));
typedef unsigned short u16x8 __attribute__((ext_vector_type(8)));
typedef float  f32x4  __attribute__((ext_vector_type(4)));

typedef const __attribute__((address_space(1))) void* gptr_t;
typedef __attribute__((address_space(3))) void* lptr_t;

// ---------------------------------------------------------------- fused prepass
__global__ __launch_bounds__(256) void prepass(const float* __restrict__ x,
                                               bf16_t* __restrict__ xb,
                                               const float* __restrict__ Wqkv,
                                               bf16_t* __restrict__ wqkvT,
                                               const float* __restrict__ Wproj,
                                               bf16_t* __restrict__ wprojT) {
    __shared__ float tile[32][33];
    const int bid = blockIdx.x;
    if (bid < 8192) {
        const size_t n = (size_t)16384 * 1024;
        const size_t stride = (size_t)8192 * 256 * 4;
        for (size_t i = ((size_t)bid * 256 + threadIdx.x) * 4; i < n; i += stride) {
            float4 v = *(const float4*)(x + i);
            bf16_t t[4];
            t[0] = (bf16_t)v.x; t[1] = (bf16_t)v.y; t[2] = (bf16_t)v.z; t[3] = (bf16_t)v.w;
            *(uint2*)(xb + i) = *(uint2*)t;
        }
        return;
    }
    const float* in;
    bf16_t* out;
    int K, N, bx, by;
    if (bid < 8192 + 3072) {
        const int t = bid - 8192;
        in = Wqkv; out = wqkvT; K = 1024; N = 3072;
        bx = t % 96; by = t / 96;
    } else {
        const int t = bid - 11264;
        in = Wproj; out = wprojT; K = 1024; N = 1024;
        bx = t & 31; by = t >> 5;
    }
    const int tx = threadIdx.x & 31, ty = threadIdx.x >> 5;   // 32 x 8
    #pragma unroll
    for (int i = 0; i < 4; i++) {
        const int k = by * 32 + ty + i * 8;
        tile[ty + i * 8][tx] = in[(size_t)k * N + bx * 32 + tx];
    }
    __syncthreads();
    #pragma unroll
    for (int i = 0; i < 4; i++) {
        const int n = bx * 32 + ty + i * 8;
        out[(size_t)n * K + by * 32 + tx] = (bf16_t)tile[tx][ty + i * 8];
    }
}

// ---------------------------------------------------------------- GEMM (B-transposed)
// Unchanged from round 7 (verified, 1030 TF): 256x256 tile, 16 waves of 64x64,
// ring of 3 K=32 slices (96 KB LDS), counted vmcnt(2), both-sides XOR swizzle,
// XCD-chunked bm strips.
template <bool BF16_OUT, bool BIAS>
__global__ __launch_bounds__(1024, 4) void gemm256q(const bf16_t* __restrict__ A,
                                                    const bf16_t* __restrict__ Bt,
                                                    void* __restrict__ Cout,
                                                    const float* __restrict__ bias,
                                                    int M, int N, int K) {
    __shared__ bf16_t ring[3][16384];   // 96 KiB

    const int tid  = threadIdx.x;
    const int lane = tid & 63, wave = tid >> 6;          // 16 waves
    const int quad = lane >> 4, l16 = lane & 15;
    const int wm = wave >> 2, wn = wave & 3;             // 4x4; wave owns 64x64 of C

    const int nbm  = M >> 8;              // 64
    const int mloc = nbm >> 3;            // 8 per XCD strip
    const int xcd  = blockIdx.x & 7;
    const int idx  = blockIdx.x >> 3;
    const int bn   = idx / mloc;
    const int bm   = xcd * mloc + (idx - bn * mloc);

    const bf16_t* Ab = A  + (size_t)bm * 256 * K;
    const bf16_t* Bb = Bt + (size_t)bn * 256 * K;

    const int srow = lane >> 2;
    const int scs  = (lane & 3) ^ ((srow >> 1) & 3);   // pre-swizzled src chunk
    const int rdo  = ((quad ^ ((l16 >> 1) & 3)) << 3); // read-side swizzled elem off

    f32x4 acc[4][4];
    #pragma unroll
    for (int i = 0; i < 4; ++i)
        #pragma unroll
        for (int j = 0; j < 4; ++j) acc[i][j] = (f32x4){0.f, 0.f, 0.f, 0.f};

#define STG(SLICE, SLOT)                                                              \
    do {                                                                              \
        __builtin_amdgcn_global_load_lds(                                             \
            (gptr_t)(Ab + (size_t)(wave * 16 + srow) * K + ((SLICE) << 5) + scs * 8), \
            (lptr_t)&ring[SLOT][wave * 512], 16, 0, 0);                               \
        __builtin_amdgcn_global_load_lds(                                             \
            (gptr_t)(Bb + (size_t)(wave * 16 + srow) * K + ((SLICE) << 5) + scs * 8), \
            (lptr_t)&ring[SLOT][8192 + wave * 512], 16, 0, 0);                        \
    } while (0)

#define BODY(G, RS, SS, DO_STAGE, WAIT_STMT)                                          \
    do {                                                                              \
        const bf16_t* sl_ = ring[RS];                                                 \
        bf16x8 af_[4], bf_[4];                                                        \
        _Pragma("unroll")                                                             \
        for (int fr = 0; fr < 4; ++fr)                                                \
            af_[fr] = *(const bf16x8*)&sl_[(wm * 64 + fr * 16 + l16) * 32 + rdo];     \
        _Pragma("unroll")                                                             \
        for (int fr = 0; fr < 4; ++fr)                                                \
            bf_[fr] =                                                                 \
                *(const bf16x8*)&sl_[8192 + (wn * 64 + fr * 16 + l16) * 32 + rdo];    \
        if (DO_STAGE) STG((G) + 2, SS);                                               \
        WAIT_STMT;                                                                    \
        __builtin_amdgcn_s_barrier();                                                 \
        __builtin_amdgcn_s_setprio(1);                                                \
        _Pragma("unroll")                                                             \
        for (int mr = 0; mr < 4; ++mr)                                                \
            _Pragma("unroll")                                                         \
            for (int nr = 0; nr < 4; ++nr)                                            \
                acc[mr][nr] = __builtin_amdgcn_mfma_f32_16x16x32_bf16(                \
                    af_[mr], bf_[nr], acc[mr][nr], 0, 0, 0);                          \
        __builtin_amdgcn_s_setprio(0);                                                \
    } while (0)

    STG(0, 0); STG(1, 1);
    asm volatile("s_waitcnt vmcnt(2)" ::: "memory");
    __builtin_amdgcn_s_barrier();

    const int NS = K >> 5;   // 32 slices
    int rs = 0, ss = 2;
    for (int g = 0; g < NS - 2; ++g) {
        BODY(g, rs, ss, true, asm volatile("s_waitcnt vmcnt(2)" ::: "memory"));
        rs = (rs == 2) ? 0 : rs + 1;
        ss = (ss == 2) ? 0 : ss + 1;
    }
    BODY(NS - 2, rs, ss, false, asm volatile("s_waitcnt vmcnt(0)" ::: "memory"));
    rs = (rs == 2) ? 0 : rs + 1;
    BODY(NS - 1, rs, ss, false, (void)0);
#undef BODY
#undef STG

    #pragma unroll
    for (int mr = 0; mr < 4; ++mr) {
        #pragma unroll
        for (int nr = 0; nr < 4; ++nr) {
            const int gcol = bn * 256 + wn * 64 + nr * 16 + l16;
            #pragma unroll
            for (int reg = 0; reg < 4; ++reg) {
                const int grow = bm * 256 + wm * 64 + mr * 16 + quad * 4 + reg;
                float v = acc[mr][nr][reg];
                if (BIAS) v += bias[gcol];
                if (BF16_OUT)
                    ((bf16_t*)Cout)[(size_t)grow * N + gcol] = (bf16_t)v;
                else
                    ((float*)Cout)[(size_t)grow * N + gcol] = v;
            }
        }
    }
}

// ---------------------------------------------------------------- block-local attention
// ROUND 8 restructure. One workgroup per (b, blk, h), 256 thr, 4 waves.
//  - q NOT staged: wave-private fragments loaded direct to VGPR (4 x b128,
//    issued first so latency hides under k/v staging).
//  - k staged via async global_load_lds into unpadded [128][64] with both-sides
//    XOR swizzle (src chunk ^ row&7 pre-swizzle; read addr ^ (l16&7)<<3) --
//    conflict-free b128 reads, no VGPR round-trip (GEMM-proven algebra).
//  - v transposed+packed b32 scatter, 3-bit chunk-XOR swizzle (r7, verified).
//  - P buffer halved to [128][72]; PV in two k-half passes. P rows are
//    wave-private -> the passes need only lgkmcnt(0)+sched_barrier (rule 18),
//    no barrier. Barriers: 3 -> 2.
//  - LDS 54272 -> 35840 B: ps overlays ks (dead after QK), vT separate.
//    4 blocks/CU = 16 waves/CU (was 12). __launch_bounds__(256,4).
//  - XCD head-grouping kept (16 heads of one (b,blk) share 768 KB of qkv ->
//    L2-resident on one XCD).
__global__ __launch_bounds__(256, 4) void attn_kernel(const bf16_t* __restrict__ qkv,
                                                      bf16_t* __restrict__ attn_out) {
    __shared__ __align__(16) char smem[35840];
    bf16_t* ks = (bf16_t*)smem;                   // [128][64] swizzled (stage phase)
    bf16_t* ps = (bf16_t*)smem;                   // [128][72] overlays ks after QK
    bf16_t* vT = (bf16_t*)(smem + 18432);         // [64][136] swizzled

    const int tid = threadIdx.x;
    const int lane = tid & 63, wave = tid >> 6;
    const int quad = lane >> 4, l16 = lane & 15;

    const int gid = blockIdx.x;
    const int xcd = gid & 7;
    const int j = gid >> 3;
    const int h = j & 15;
    const int blkhi = (j >> 4) & 3;
    const int b = j >> 6;
    const int blk = blkhi * 8 + xcd;
    const int row0 = (b * 32 + blk) * 128;   // row base in [16384]
    const int LDQ = 3072;

    // ---- q fragments direct to registers (issued first; drained at barrier)
    bf16x8 aq[2][2];
    #pragma unroll
    for (int mr = 0; mr < 2; mr++)
        #pragma unroll
        for (int ksl = 0; ksl < 2; ksl++)
            aq[mr][ksl] = *(const bf16x8*)(qkv +
                (size_t)(row0 + wave * 32 + mr * 16 + l16) * LDQ + h * 64 +
                ksl * 32 + quad * 8);

    // ---- stage k: async global_load_lds, pre-swizzled source chunk
    {
        const int r8 = lane >> 3;                 // 0..7 row within 8-row group
        const int cs = (lane & 7) ^ r8;           // chunk ^ (row&7)
        #pragma unroll
        for (int i = 0; i < 4; i++) {
            __builtin_amdgcn_global_load_lds(
                (gptr_t)(qkv + (size_t)(row0 + i * 32 + wave * 8 + r8) * LDQ +
                         1024 + h * 64 + cs * 8),
                (lptr_t)&ks[(i * 32 + wave * 8) * 64], 16, 0, 0);
        }
    }
    // ---- stage v transposed: vT[c][k ^ ((c>>3)&7)<<3], b32-packed row pairs
    for (int t = tid; t < 64 * 8; t += 256) {
        const int r2 = t >> 3;               // rows 2r2, 2r2+1
        const int c0 = (t & 7) * 8;
        const bf16_t* vsrc = qkv + (size_t)(row0 + 2 * r2) * LDQ + h * 64 + 2048 + c0;
        u16x8 v0 = *(const u16x8*)(vsrc);
        u16x8 v1 = *(const u16x8*)(vsrc + LDQ);
        const int X = (t & 7) << 3;
        #pragma unroll
        for (int jj = 0; jj < 8; jj++) {
            unsigned int pv = (unsigned int)v0[jj] | ((unsigned int)v1[jj] << 16);
            *(unsigned int*)&vT[(c0 + jj) * 136 + ((2 * r2) ^ X)] = pv;
        }
    }
    __syncthreads();   // drains q loads (vmcnt), k gload_lds (vmcnt), vT writes (lgkm)

    // ---- S = q k^T / 8 : wave handles rows [wave*32, +32) x 128 cols
    f32x4 sfrag[2][8];
    #pragma unroll
    for (int mr = 0; mr < 2; mr++)
        #pragma unroll
        for (int nc = 0; nc < 8; nc++)
            sfrag[mr][nc] = (f32x4){0.f, 0.f, 0.f, 0.f};

    #pragma unroll
    for (int ksl = 0; ksl < 2; ksl++) {
        bf16x8 bk[8];
        #pragma unroll
        for (int nc = 0; nc < 8; nc++)
            bk[nc] = *(const bf16x8*)&ks[(nc * 16 + l16) * 64 +
                                         (((ksl * 4 + quad) ^ (l16 & 7)) << 3)];
        #pragma unroll
        for (int mr = 0; mr < 2; mr++)
            #pragma unroll
            for (int nc = 0; nc < 8; nc++)
                sfrag[mr][nc] = __builtin_amdgcn_mfma_f32_16x16x32_bf16(
                    aq[mr][ksl], bk[nc], sfrag[mr][nc], 0, 0, 0);
    }

    // ---- scale + causal mask (C-layout: row=quad*4+reg, col=nc*16+l16)
    #pragma unroll
    for (int mr = 0; mr < 2; mr++) {
        #pragma unroll
        for (int nc = 0; nc < 8; nc++) {
            #pragma unroll
            for (int reg = 0; reg < 4; reg++) {
                const int row = wave * 32 + mr * 16 + quad * 4 + reg;
                const int col = nc * 16 + l16;
                float s = sfrag[mr][nc][reg] * 0.125f;
                if (col > row) s = -INFINITY;
                sfrag[mr][nc][reg] = s;
            }
        }
    }

    // ---- softmax per row
    #pragma unroll
    for (int mr = 0; mr < 2; mr++) {
        #pragma unroll
        for (int reg = 0; reg < 4; reg++) {
            float m = -INFINITY;
            #pragma unroll
            for (int nc = 0; nc < 8; nc++) m = fmaxf(m, sfrag[mr][nc][reg]);
            #pragma unroll
            for (int off = 1; off < 16; off <<= 1) m = fmaxf(m, __shfl_xor(m, off));
            float sum = 0.f;
            #pragma unroll
            for (int nc = 0; nc < 8; nc++) {
                float e = __expf(sfrag[mr][nc][reg] - m);
                sfrag[mr][nc][reg] = e;
                sum += e;
            }
            #pragma unroll
            for (int off = 1; off < 16; off <<= 1) sum += __shfl_xor(sum, off);
            const float inv = 1.0f / (sum + 1e-6f);
            #pragma unroll
            for (int nc = 0; nc < 8; nc++) sfrag[mr][nc][reg] *= inv;
        }
    }

    __syncthreads();   // all waves done reading ks before ps overlays it

    // ---- O = P @ V in two k-half passes; P rows are wave-private (no barrier)
    f32x4 oacc[2][4];
    #pragma unroll
    for (int mr = 0; mr < 2; mr++)
        #pragma unroll
        for (int nd = 0; nd < 4; nd++)
            oacc[mr][nd] = (f32x4){0.f, 0.f, 0.f, 0.f};

    #pragma unroll
    for (int half = 0; half < 2; half++) {
        // write P cols [half*64, +64) for own rows into ps[128][72]
        #pragma unroll
        for (int mr = 0; mr < 2; mr++)
            #pragma unroll
            for (int nc = 0; nc < 4; nc++)
                #pragma unroll
                for (int reg = 0; reg < 4; reg++) {
                    const int row = wave * 32 + mr * 16 + quad * 4 + reg;
                    ps[row * 72 + nc * 16 + l16] = (bf16_t)sfrag[mr][half * 4 + nc][reg];
                }
        asm volatile("s_waitcnt lgkmcnt(0)" ::: "memory");
        __builtin_amdgcn_sched_barrier(0);    // rule 18: keep MFMA after the wait
        #pragma unroll
        for (int kh = 0; kh < 2; kh++) {
            const int G = half * 2 + kh;      // global 32-wide k-slice 0..3
            bf16x8 ap[2];
            #pragma unroll
            for (int mr = 0; mr < 2; mr++)
                ap[mr] = *(const bf16x8*)&ps[(wave * 32 + mr * 16 + l16) * 72 +
                                             kh * 32 + quad * 8];
            #pragma unroll
            for (int nd = 0; nd < 4; nd++) {
                const int c2 = nd * 16 + l16;
                const int X2 = ((c2 >> 3) & 7) << 3;
                bf16x8 bv = *(const bf16x8*)&vT[c2 * 136 + ((G * 32 + quad * 8) ^ X2)];
                #pragma unroll
                for (int mr = 0; mr < 2; mr++)
                    oacc[mr][nd] = __builtin_amdgcn_mfma_f32_16x16x32_bf16(
                        ap[mr], bv, oacc[mr][nd], 0, 0, 0);
            }
        }
    }

    // ---- store O bf16 into attn buffer [16384][1024]
    #pragma unroll
    for (int mr = 0; mr < 2; mr++)
        #pragma unroll
        for (int nd = 0; nd < 4; nd++)
            #pragma unroll
            for (int reg = 0; reg < 4; reg++) {
                const int row = row0 + wave * 32 + mr * 16 + quad * 4 + reg;
                const int col = h * 64 + nd * 16 + l16;
                attn_out[(size_t)row * 1024 + col] = (bf16_t)oacc[mr][nd][reg];
            }
}

// ---------------------------------------------------------------- launch
extern "C" void kernel_launch(void* const* d_in, const int* in_sizes, int n_in,
                              void* d_out, int out_size, void* d_ws, size_t ws_size,
                              hipStream_t stream) {
    const float* x     = (const float*)d_in[0];   // [4,4096,1024]
    const float* Wqkv  = (const float*)d_in[1];   // [1024,3072]
    const float* Wproj = (const float*)d_in[2];   // [1024,1024]
    const float* bproj = (const float*)d_in[3];   // [1024]

    const int M = 16384, C = 1024, N1 = 3072;

    // workspace carve (bytes): all 16B aligned
    char* ws = (char*)d_ws;
    bf16_t* xb     = (bf16_t*)(ws);                                   // 32 MB
    bf16_t* wqkvT  = (bf16_t*)(ws + 33554432);                        //  6 MB  [3072][1024]
    bf16_t* wprojT = (bf16_t*)(ws + 39845888);                        //  2 MB  [1024][1024]
    bf16_t* qkvb   = (bf16_t*)(ws + 41943040);                        // 96 MB  [16384][3072]
    bf16_t* attnb  = (bf16_t*)(ws + 142606336);                       // 32 MB  [16384][1024]
    // total 168 MB

    prepass<<<12288, 256, 0, stream>>>(x, xb, Wqkv, wqkvT, Wproj, wprojT);

    // 1D grids, XCD-chunk-swizzled in-kernel: GEMM1 768 = 8*96, GEMM2 256 = 8*32
    gemm256q<true, false><<<(N1 / 256) * (M / 256), 1024, 0, stream>>>(
        xb, wqkvT, (void*)qkvb, nullptr, M, N1, C);

    attn_kernel<<<2048, 256, 0, stream>>>(qkvb, attnb);

    gemm256q<false, true><<<(C / 256) * (M / 256), 1024, 0, stream>>>(
        attnb, wprojT, d_out, bproj, M, C, C);
}